// Round 17
// baseline (20411.290 us; speedup 1.0000x reference)
//
#include <hip/hip_runtime.h>

// GRU: B=256, T=512, F=256, H=512, C=10  (MI355X / gfx950)
// Round 17: ELIMINATE inter-WG exchange. One 1024-thread WG owns a 16-row
// group with ALL 512 columns: 16 waves x 32 cols (2 col-blocks). Weights
// (3 gates x 2 blocks x 16 K-frags = 384 VGPR) in registers; 16 waves x 512
// VGPR exactly fill a CU (workers get exclusive CUs). h and r*h live in LDS;
// exchange = __syncthreads (~100cy), NOT agent-scope LIC round trips (~2us).
// Only global traffic in the loop: xproj prefetch (hidden under MFMA).
// R16's sc0 flag path REVERTED (4x regression; sc0 line closed).
// NOTE: SQ_LDS_BANK_CONFLICT is saturated/bogus for these kernels.

#define BB 256
#define TT 512
#define FF 256
#define HH 512
#define HX 1536
#define GROUP_WGS 8
#define LROW 520                     // padded LDS row stride (shorts)

typedef short short8 __attribute__((ext_vector_type(8)));
typedef short short4v __attribute__((ext_vector_type(4)));
typedef float float4v __attribute__((ext_vector_type(4)));
typedef unsigned long long u64;
typedef unsigned short ushort;

// ws layout (bytes)
#define WFRAG_OFF 0
#define WFRAG_BYTES (32 * 3 * 24 * 64 * 8 * 2)            // 2,359,296
#define HBUF_OFF (WFRAG_OFF + WFRAG_BYTES)                 // bf16 h   [256][512]
#define RHBUF_OFF (HBUF_OFF + BB * HH * 2)                 // bf16 r*h [256][512]
#define HFIN_OFF (RHBUF_OFF + BB * HH * 2)                 // f32 h_final
#define CTRL_OFF (HFIN_OFF + BB * HH * 4)                  // claims + done + flags
#define CTRL_BYTES 16384
#define XBASE_OFF (CTRL_OFF + CTRL_BYTES)
#define XB_BYTES ((size_t)BB * TT * FF * 2)                // 67 MB (mode 1)
#define XPROJ_BYTES ((size_t)BB * TT * HX * 2)             // 402 MB (mode 2)
#define WS_M2 ((size_t)XBASE_OFF + XPROJ_BYTES)
#define WS_M1 ((size_t)XBASE_OFF + XB_BYTES)

__device__ __forceinline__ short f2bf(float f) {
  unsigned u = __builtin_bit_cast(unsigned, f);
  u += 0x7fffu + ((u >> 16) & 1u);            // RNE to bf16
  return (short)(u >> 16);
}
__device__ __forceinline__ float bf2f(ushort u) {
  return __builtin_bit_cast(float, (unsigned)u << 16);
}
__device__ __forceinline__ float sigm(float v) { return 1.0f / (1.0f + __expf(-v)); }
__device__ __forceinline__ float tanh_(float v) { return 2.0f / (1.0f + __expf(-2.0f * v)) - 1.0f; }
__device__ __forceinline__ float4v mfma_bf16(short8 a, short8 b, float4v c) {
  return __builtin_amdgcn_mfma_f32_16x16x32_bf16(a, b, c, 0, 0, 0);
}

// ---- weight prep: f32 [768][512] -> bf16 MFMA B-fragments ----
__global__ void prep_w(const float* __restrict__ Wz, const float* __restrict__ Wr,
                       const float* __restrict__ Wh, short* __restrict__ wfrag) {
  int id = blockIdx.x * 256 + threadIdx.x;     // 576*256 == 32*3*24*64
  int lane = id & 63;
  int rest = id >> 6;
  int kk = rest % 24;
  int gc = rest / 24;
  int g = gc % 3;
  int cb = gc / 3;
  if (cb >= 32) return;
  const float* W = (g == 0) ? Wz : ((g == 1) ? Wr : Wh);
  int n = cb * 16 + (lane & 15);
  int kbase = kk * 32 + (lane >> 4) * 8;
  short8 v;
#pragma unroll
  for (int j = 0; j < 8; ++j) v[j] = f2bf(W[(size_t)(kbase + j) * HH + n]);
  *(((short8*)wfrag) + id) = v;
}

// ---- x prep (mode 1 fallback): f32 -> bf16 ----
__global__ void xprep(const float* __restrict__ x, short* __restrict__ xb) {
  size_t i = (size_t)blockIdx.x * 256 + threadIdx.x;
  const float4v* src = (const float4v*)x;
  float4v a = src[i * 2], b = src[i * 2 + 1];
  short8 v;
  v[0] = f2bf(a[0]); v[1] = f2bf(a[1]); v[2] = f2bf(a[2]); v[3] = f2bf(a[3]);
  v[4] = f2bf(b[0]); v[5] = f2bf(b[1]); v[6] = f2bf(b[2]); v[7] = f2bf(b[3]);
  *(((short8*)xb) + i) = v;
}

// ---- xproj GEMM (mode 2): [BT,256] @ x-part weights -> bf16 [BT][3*512], bias folded ----
__global__ __launch_bounds__(256) void xproj_gemm(
    const float* __restrict__ x, const short* __restrict__ wfrag,
    const float* __restrict__ bz, const float* __restrict__ br,
    const float* __restrict__ bh, short* __restrict__ xp) {
  const int w = threadIdx.x >> 6, l = threadIdx.x & 63;
  const int l15 = l & 15, lhi = l >> 4;
  const size_t row0 = (size_t)blockIdx.x * 64 + w * 16;
  const float* xl = x + (row0 + l15) * FF + lhi * 8;
  short8 xf[8];
#pragma unroll
  for (int kx = 0; kx < 8; ++kx) {
    float4v a = *(const float4v*)(xl + kx * 32);
    float4v b2 = *(const float4v*)(xl + kx * 32 + 4);
    short8 v;
    v[0] = f2bf(a[0]); v[1] = f2bf(a[1]); v[2] = f2bf(a[2]); v[3] = f2bf(a[3]);
    v[4] = f2bf(b2[0]); v[5] = f2bf(b2[1]); v[6] = f2bf(b2[2]); v[7] = f2bf(b2[3]);
    xf[kx] = v;
  }
  const short8* wf = (const short8*)wfrag;
#pragma unroll 1
  for (int cb = 0; cb < 32; ++cb) {
#pragma unroll
    for (int g = 0; g < 3; ++g) {
      const float* bias = (g == 0) ? bz : ((g == 1) ? br : bh);
      float bv = bias[cb * 16 + l15];
      float4v acc = {bv, bv, bv, bv};
#pragma unroll
      for (int kx = 0; kx < 8; ++kx)
        acc = mfma_bf16(xf[kx], wf[((cb * 3 + g) * 24 + 16 + kx) * 64 + l], acc);
#pragma unroll
      for (int i = 0; i < 4; ++i)
        xp[(row0 + lhi * 4 + i) * HX + g * 512 + cb * 16 + l15] = f2bf(acc[i]);
    }
  }
}

// =========== single-WG-per-group GRU: 1024 thr, LDS-only exchange ===========
__global__ __launch_bounds__(1024, 1) void gru1w(
    const short* __restrict__ xp, const short* __restrict__ wfrag,
    float* __restrict__ hfin, int* __restrict__ ctrl) {
  __shared__ short lds[2 * 16 * LROW];   // buf0 = h tile, buf1 = rh tile
  int* done = ctrl + 192;

  if (blockIdx.x >= 16) {
    // burner: keep clocks up; moderate all-lane poll cadence
    float a = (float)threadIdx.x;
    for (;;) {
#pragma unroll 64
      for (int i = 0; i < 1024; ++i) a = __builtin_fmaf(a, 1.0000001f, 1.0f);
      asm volatile("" : "+v"(a));
      if (__hip_atomic_load(done, __ATOMIC_RELAXED, __HIP_MEMORY_SCOPE_AGENT) >= 16)
        break;
    }
    asm volatile("" :: "v"(a));
    return;
  }

  const int rb = blockIdx.x * 16;              // this WG's 16 batch rows
  const int tid = threadIdx.x;
  const int wv = tid >> 6;                     // wave 0..15
  const int l = tid & 63, l15 = l & 15, lhi = l >> 4;
  const int cb0 = wv * 2, cb1 = wv * 2 + 1;    // 16-col blocks
  const int c0 = cb0 * 16, c1 = cb1 * 16;      // col bases

  // ---- weights (h-part): 6 x 16 short8 = 384 VGPR ----
  const short8* wf = (const short8*)wfrag;
  short8 wz0[16], wz1[16], wr0[16], wr1[16], wh0[16], wh1[16];
#pragma unroll
  for (int kk = 0; kk < 16; ++kk) {
    wz0[kk] = wf[((cb0 * 3 + 0) * 24 + kk) * 64 + l];
    wz1[kk] = wf[((cb1 * 3 + 0) * 24 + kk) * 64 + l];
    wr0[kk] = wf[((cb0 * 3 + 1) * 24 + kk) * 64 + l];
    wr1[kk] = wf[((cb1 * 3 + 1) * 24 + kk) * 64 + l];
    wh0[kk] = wf[((cb0 * 3 + 2) * 24 + kk) * 64 + l];
    wh1[kk] = wf[((cb1 * 3 + 2) * 24 + kk) * 64 + l];
  }

  // xproj row-base pointers (4 rows this lane accumulates)
  const short* xpp[4];
#pragma unroll
  for (int i = 0; i < 4; ++i)
    xpp[i] = xp + (size_t)(rb + lhi * 4 + i) * TT * HX;

  float4v h0 = {0, 0, 0, 0}, h1 = {0, 0, 0, 0};
  float4v z0, z1;
  ushort nz0[4], nr0[4], nh0[4], nz1[4], nr1[4], nh1[4];

#define DSFRAG(BUF, KK)                                                      \
  (*(const short8*)&lds[(BUF) * 16 * LROW + l15 * LROW + (KK) * 32 + lhi * 8])

  // prologue: h tile = zeros; stage xproj(t=0)
  for (int i = tid; i < 16 * LROW; i += 1024) lds[i] = 0;
#pragma unroll
  for (int i = 0; i < 4; ++i) {
    nz0[i] = *(const ushort*)(xpp[i] + 0 * 512 + c0 + l15);
    nr0[i] = *(const ushort*)(xpp[i] + 1 * 512 + c0 + l15);
    nh0[i] = *(const ushort*)(xpp[i] + 2 * 512 + c0 + l15);
    nz1[i] = *(const ushort*)(xpp[i] + 0 * 512 + c1 + l15);
    nr1[i] = *(const ushort*)(xpp[i] + 1 * 512 + c1 + l15);
    nh1[i] = *(const ushort*)(xpp[i] + 2 * 512 + c1 + l15);
  }
  __syncthreads();

#pragma unroll 1
  for (int t = 0; t < TT; ++t) {
    const bool more = (t + 1 < TT);
    // ===== P1: z,r from h tile (buf0); write rh tile (buf1) =====
    float4v az0, ar0, az1, ar1;
#pragma unroll
    for (int i = 0; i < 4; ++i) {
      az0[i] = bf2f(nz0[i]); ar0[i] = bf2f(nr0[i]);
      az1[i] = bf2f(nz1[i]); ar1[i] = bf2f(nr1[i]);
    }
#pragma unroll
    for (int kk = 0; kk < 16; ++kk) {
      short8 A = DSFRAG(0, kk);
      az0 = mfma_bf16(A, wz0[kk], az0);
      ar0 = mfma_bf16(A, wr0[kk], ar0);
      az1 = mfma_bf16(A, wz1[kk], az1);
      ar1 = mfma_bf16(A, wr1[kk], ar1);
    }
#pragma unroll
    for (int i = 0; i < 4; ++i) {
      z0[i] = sigm(az0[i]);
      z1[i] = sigm(az1[i]);
      float rv0 = sigm(ar0[i]);
      float rv1 = sigm(ar1[i]);
      int row = lhi * 4 + i;
      lds[16 * LROW + row * LROW + c0 + l15] = f2bf(rv0 * h0[i]);
      lds[16 * LROW + row * LROW + c1 + l15] = f2bf(rv1 * h1[i]);
    }
    __syncthreads();

    // ===== P2: h_tilde from rh tile (buf1); update h; write h tile =====
    float4v ah0, ah1;
#pragma unroll
    for (int i = 0; i < 4; ++i) { ah0[i] = bf2f(nh0[i]); ah1[i] = bf2f(nh1[i]); }
    // issue xproj(t+1) prefetch now -- lands during the MFMA loop below
    if (more) {
      size_t toff = (size_t)(t + 1) * HX;
#pragma unroll
      for (int i = 0; i < 4; ++i) {
        nz0[i] = *(const ushort*)(xpp[i] + toff + 0 * 512 + c0 + l15);
        nr0[i] = *(const ushort*)(xpp[i] + toff + 1 * 512 + c0 + l15);
        nh0[i] = *(const ushort*)(xpp[i] + toff + 2 * 512 + c0 + l15);
        nz1[i] = *(const ushort*)(xpp[i] + toff + 0 * 512 + c1 + l15);
        nr1[i] = *(const ushort*)(xpp[i] + toff + 1 * 512 + c1 + l15);
        nh1[i] = *(const ushort*)(xpp[i] + toff + 2 * 512 + c1 + l15);
      }
    }
#pragma unroll
    for (int kk = 0; kk < 16; ++kk) {
      short8 A = DSFRAG(1, kk);
      ah0 = mfma_bf16(A, wh0[kk], ah0);
      ah1 = mfma_bf16(A, wh1[kk], ah1);
    }
#pragma unroll
    for (int i = 0; i < 4; ++i) {
      float hv0 = tanh_(ah0[i]);
      float hv1 = tanh_(ah1[i]);
      h0[i] = (1.0f - z0[i]) * h0[i] + z0[i] * hv0;
      h1[i] = (1.0f - z1[i]) * h1[i] + z1[i] * hv1;
      int row = lhi * 4 + i;
      if (more) {
        lds[row * LROW + c0 + l15] = f2bf(h0[i]);
        lds[row * LROW + c1 + l15] = f2bf(h1[i]);
      } else {
        hfin[(size_t)(rb + row) * HH + c0 + l15] = h0[i];
        hfin[(size_t)(rb + row) * HH + c1 + l15] = h1[i];
      }
    }
    if (more) __syncthreads();
  }

  if (tid == 0)
    __hip_atomic_fetch_add(done, 1, __ATOMIC_RELAXED, __HIP_MEMORY_SCOPE_AGENT);
#undef DSFRAG
}

// ================== fallback (modes 1/0): R8/R14-style kernel ==================
__device__ __forceinline__ void wait_flags(const int* fl, int tgt) {
  const int* p = fl + (threadIdx.x & 31);
  for (;;) {
    int v = __hip_atomic_load(p, __ATOMIC_RELAXED, __HIP_MEMORY_SCOPE_AGENT);
    if (!__any(v < tgt)) break;
  }
}
__device__ __forceinline__ void arrive_flag(int* fl, int wid, int val) {
  asm volatile("s_waitcnt vmcnt(0)" ::: "memory");
  if ((threadIdx.x & 63) == 0)
    __hip_atomic_store(fl + wid, val, __ATOMIC_RELAXED, __HIP_MEMORY_SCOPE_AGENT);
}
__device__ __forceinline__ short8 ld_frag(const short* p) {
  const u64* q = (const u64*)p;
  u64 lo = __hip_atomic_load(q, __ATOMIC_RELAXED, __HIP_MEMORY_SCOPE_AGENT);
  u64 hi = __hip_atomic_load(q + 1, __ATOMIC_RELAXED, __HIP_MEMORY_SCOPE_AGENT);
  short4v l4 = __builtin_bit_cast(short4v, lo);
  short4v h4 = __builtin_bit_cast(short4v, hi);
  return __builtin_shufflevector(l4, h4, 0, 1, 2, 3, 4, 5, 6, 7);
}
__device__ __forceinline__ void gate_phase1(const short* hb_lane,
    const short8* wz, const short8* wr, float4v azx, float4v arx,
    float bz, float br, float4v& z, float4v& rr) {
  short8 a[16];
#pragma unroll
  for (int kk = 0; kk < 16; ++kk) a[kk] = ld_frag(hb_lane + kk * 32);
  float4v az = azx, ar = arx;
#pragma unroll
  for (int kk = 0; kk < 16; ++kk) {
    az = mfma_bf16(a[kk], wz[kk], az);
    ar = mfma_bf16(a[kk], wr[kk], ar);
  }
#pragma unroll
  for (int i = 0; i < 4; ++i) {
    z[i] = sigm(az[i] + bz);
    rr[i] = sigm(ar[i] + br);
  }
}
__device__ __forceinline__ float4v gate_phase2(const short* rh_lane,
    const short8* wh, float4v ahx, float bh, float4v z, float4v h_loc) {
  short8 a[16];
#pragma unroll
  for (int kk = 0; kk < 16; ++kk) a[kk] = ld_frag(rh_lane + kk * 32);
  float4v ah = ahx;
#pragma unroll
  for (int kk = 0; kk < 16; ++kk)
    ah = mfma_bf16(a[kk], wh[kk], ah);
  float4v hn;
#pragma unroll
  for (int i = 0; i < 4; ++i) {
    float hv = tanh_(ah[i] + bh);
    hn[i] = (1.0f - z[i]) * h_loc[i] + z[i] * hv;
  }
  return hn;
}
template <bool XB>
__device__ __forceinline__ void load_xf(short8 (&xf)[8], const short* xb_l,
                                        const float* xf_l, int t) {
#pragma unroll
  for (int kx = 0; kx < 8; ++kx) {
    if constexpr (XB) {
      xf[kx] = *(const short8*)(xb_l + (size_t)t * FF + kx * 32);
    } else {
      const float* xl = xf_l + (size_t)t * FF;
      float4v a = *(const float4v*)(xl + kx * 32);
      float4v b2 = *(const float4v*)(xl + kx * 32 + 4);
      short8 v;
      v[0] = f2bf(a[0]); v[1] = f2bf(a[1]); v[2] = f2bf(a[2]); v[3] = f2bf(a[3]);
      v[4] = f2bf(b2[0]); v[5] = f2bf(b2[1]); v[6] = f2bf(b2[2]); v[7] = f2bf(b2[3]);
      xf[kx] = v;
    }
  }
}
__device__ __forceinline__ void prime_x(const short8 (&xf)[8],
    const short8* wz, const short8* wr, const short8* wh,
    float4v& azx, float4v& arx, float4v& ahx) {
  azx = (float4v){0.f, 0.f, 0.f, 0.f};
  arx = (float4v){0.f, 0.f, 0.f, 0.f};
  ahx = (float4v){0.f, 0.f, 0.f, 0.f};
#pragma unroll
  for (int kx = 0; kx < 8; ++kx) {
    azx = mfma_bf16(xf[kx], wz[16 + kx], azx);
    arx = mfma_bf16(xf[kx], wr[16 + kx], arx);
    ahx = mfma_bf16(xf[kx], wh[16 + kx], ahx);
  }
}
template <int XM>
__global__ __launch_bounds__(256, 1) void gru_kernel(
    const void* __restrict__ xv, const short* __restrict__ wfrag,
    short* __restrict__ hbuf, short* __restrict__ rhbuf,
    float* __restrict__ hfin, int* __restrict__ ctrl,
    const float* __restrict__ bzv, const float* __restrict__ brv,
    const float* __restrict__ bhv) {
  __shared__ int s_slot, s_xcc;
  if (threadIdx.x == 0) {
    unsigned xcc;
    asm volatile("s_getreg_b32 %0, hwreg(HW_REG_XCC_ID)" : "=s"(xcc));
    xcc &= 7u;
    s_xcc = (int)xcc;
    s_slot = atomicAdd(ctrl + xcc * 16, 1);
  }
  __syncthreads();
  const int slot = s_slot;
  if (slot >= GROUP_WGS) return;
  const int group = s_xcc;
  const int member = slot;
  const int tid = threadIdx.x;
  const int w = tid >> 6;
  const int l = tid & 63;
  const int l15 = l & 15;
  const int lhi = l >> 4;
  const int cbg = member * 4 + w;
  const int jc = cbg * 16;
  const int rbA = group * 32;
  const int rbB = rbA + 16;
  const short8* wf = (const short8*)wfrag;
  short8 wz[24], wr[24], wh[24];
#pragma unroll
  for (int kk = 0; kk < 24; ++kk) wz[kk] = wf[((cbg * 3 + 0) * 24 + kk) * 64 + l];
#pragma unroll
  for (int kk = 0; kk < 24; ++kk) wr[kk] = wf[((cbg * 3 + 1) * 24 + kk) * 64 + l];
#pragma unroll
  for (int kk = 0; kk < 24; ++kk) wh[kk] = wf[((cbg * 3 + 2) * 24 + kk) * 64 + l];
  const float bz = bzv[jc + l15], br = brv[jc + l15], bh = bhv[jc + l15];
  const int drowA = rbA + lhi * 4, drowB = rbB + lhi * 4;
  const int dcol = jc + l15;
  const short* hbA = hbuf + (size_t)(rbA + l15) * HH + lhi * 8;
  const short* hbB = hbuf + (size_t)(rbB + l15) * HH + lhi * 8;
  const short* rhA = rhbuf + (size_t)(rbA + l15) * HH + lhi * 8;
  const short* rhB = rhbuf + (size_t)(rbB + l15) * HH + lhi * 8;
  const float* xfA32 = (XM == 0) ? ((const float*)xv + (size_t)(rbA + l15) * TT * FF + lhi * 8) : nullptr;
  const float* xfB32 = (XM == 0) ? ((const float*)xv + (size_t)(rbB + l15) * TT * FF + lhi * 8) : nullptr;
  const short* xbA = (XM == 1) ? ((const short*)xv + (size_t)(rbA + l15) * TT * FF + lhi * 8) : nullptr;
  const short* xbB = (XM == 1) ? ((const short*)xv + (size_t)(rbB + l15) * TT * FF + lhi * 8) : nullptr;
  float4v h_locA = {0.f, 0.f, 0.f, 0.f}, h_locB = {0.f, 0.f, 0.f, 0.f};
  int* fb = ctrl + 256 + 1024 + group * 256;
  int* rhAf = fb, * rhBf = fb + 32, * hAf = fb + 64, * hBf = fb + 96;
  float4v azxA, arxA, ahxA, azxB, arxB, ahxB;
  {
    short8 xf[8];
    load_xf<XM == 1>(xf, xbA, xfA32, 0);
    prime_x(xf, wz, wr, wh, azxA, arxA, ahxA);
    load_xf<XM == 1>(xf, xbB, xfB32, 0);
    prime_x(xf, wz, wr, wh, azxB, arxB, ahxB);
  }
#pragma unroll 1
  for (int t = 0; t < TT; ++t) {
    if (t) wait_flags(hAf, t);
    float4v zA, rrA;
    gate_phase1(hbA, wz, wr, azxA, arxA, bz, br, zA, rrA);
#pragma unroll
    for (int i = 0; i < 4; ++i)
      rhbuf[(size_t)(drowA + i) * HH + dcol] = f2bf(rrA[i] * h_locA[i]);
    arrive_flag(rhAf, cbg, t + 1);
    if (t) wait_flags(hBf, t);
    float4v zB, rrB;
    gate_phase1(hbB, wz, wr, azxB, arxB, bz, br, zB, rrB);
#pragma unroll
    for (int i = 0; i < 4; ++i)
      rhbuf[(size_t)(drowB + i) * HH + dcol] = f2bf(rrB[i] * h_locB[i]);
    arrive_flag(rhBf, cbg, t + 1);
    wait_flags(rhAf, t + 1);
    h_locA = gate_phase2(rhA, wh, ahxA, bh, zA, h_locA);
    if (t + 1 < TT) {
#pragma unroll
      for (int i = 0; i < 4; ++i)
        hbuf[(size_t)(drowA + i) * HH + dcol] = f2bf(h_locA[i]);
      arrive_flag(hAf, cbg, t + 1);
    } else {
#pragma unroll
      for (int i = 0; i < 4; ++i)
        hfin[(size_t)(drowA + i) * HH + dcol] = h_locA[i];
    }
    wait_flags(rhBf, t + 1);
    h_locB = gate_phase2(rhB, wh, ahxB, bh, zB, h_locB);
    if (t + 1 < TT) {
#pragma unroll
      for (int i = 0; i < 4; ++i)
        hbuf[(size_t)(drowB + i) * HH + dcol] = f2bf(h_locB[i]);
      arrive_flag(hBf, cbg, t + 1);
    } else {
#pragma unroll
      for (int i = 0; i < 4; ++i)
        hfin[(size_t)(drowB + i) * HH + dcol] = h_locB[i];
    }
    if (t + 1 < TT) {
      short8 xf[8];
      load_xf<XM == 1>(xf, xbA, xfA32, t + 1);
      prime_x(xf, wz, wr, wh, azxA, arxA, ahxA);
      load_xf<XM == 1>(xf, xbB, xfB32, t + 1);
      prime_x(xf, wz, wr, wh, azxB, arxB, ahxB);
    }
  }
}

// out[b, c] = h_final[b,:] @ fc_w[:,c] + fc_b[c]
__global__ void fc_kernel(const float* __restrict__ hfin, const float* __restrict__ fw,
                          const float* __restrict__ fb, float* __restrict__ out) {
  int b = blockIdx.x;
  int tid = threadIdx.x;  // 64
  float p[10];
#pragma unroll
  for (int c = 0; c < 10; ++c) p[c] = 0.f;
  for (int k = tid; k < HH; k += 64) {
    float hv = hfin[(size_t)b * HH + k];
#pragma unroll
    for (int c = 0; c < 10; ++c) p[c] += hv * fw[k * 10 + c];
  }
#pragma unroll
  for (int c = 0; c < 10; ++c) {
    float v = p[c];
    for (int off = 32; off > 0; off >>= 1) v += __shfl_down(v, off);
    if (tid == 0) out[b * 10 + c] = v + fb[c];
  }
}

extern "C" void kernel_launch(void* const* d_in, const int* in_sizes, int n_in,
                              void* d_out, int out_size, void* d_ws, size_t ws_size,
                              hipStream_t stream) {
  const float* x = (const float*)d_in[0];
  const float* Wz_w = (const float*)d_in[1];
  const float* Wz_b = (const float*)d_in[2];
  const float* Wr_w = (const float*)d_in[3];
  const float* Wr_b = (const float*)d_in[4];
  const float* Wh_w = (const float*)d_in[5];
  const float* Wh_b = (const float*)d_in[6];
  const float* fc_w = (const float*)d_in[7];
  const float* fc_b = (const float*)d_in[8];

  char* ws = (char*)d_ws;
  short* wfrag = (short*)(ws + WFRAG_OFF);
  short* hbuf = (short*)(ws + HBUF_OFF);
  short* rhbuf = (short*)(ws + RHBUF_OFF);
  float* hfin = (float*)(ws + HFIN_OFF);
  int* ctrl = (int*)(ws + CTRL_OFF);
  short* xbase = (short*)(ws + XBASE_OFF);

  // h0 = 0 (mode 1/0 path), ctrl (claims + done) = 0 (EVERY launch)
  hipMemsetAsync(hbuf, 0, BB * HH * 2, stream);
  hipMemsetAsync(ctrl, 0, CTRL_BYTES, stream);

  prep_w<<<576, 256, 0, stream>>>(Wz_w, Wr_w, Wh_w, wfrag);

  if (ws_size >= WS_M2) {
    xproj_gemm<<<BB * TT / 64, 256, 0, stream>>>(x, wfrag, Wz_b, Wr_b, Wh_b, xbase);
    gru1w<<<144, 1024, 0, stream>>>(xbase, wfrag, hfin, ctrl);
  } else if (ws_size >= WS_M1) {
    xprep<<<(BB * TT * FF / 8) / 256, 256, 0, stream>>>(x, xbase);
    gru_kernel<1><<<256, 256, 0, stream>>>(xbase, wfrag, hbuf, rhbuf, hfin, ctrl,
                                           Wz_b, Wr_b, Wh_b);
  } else {
    gru_kernel<0><<<256, 256, 0, stream>>>(x, wfrag, hbuf, rhbuf, hfin, ctrl,
                                           Wz_b, Wr_b, Wh_b);
  }
  fc_kernel<<<BB, 64, 0, stream>>>(hfin, fc_w, fc_b, (float*)d_out);
}

// Round 18
// 20406.444 us; speedup vs baseline: 1.0002x; 1.0002x over previous
//
#include <hip/hip_runtime.h>

// GRU: B=256, T=512, F=256, H=512, C=10  (MI355X / gfx950)
// Round 18 = Round 17 with the VGPR-budget bug fixed: __launch_bounds__(1024,4)
// (2nd arg = min waves/EU; for 16-wave WGs, 4 waves/EU == 1 WG/CU == 512-VGPR
// budget). R17's (1024,1) let the allocator target high occupancy -> 64 VGPRs
// -> all 384 weight registers spilled to scratch (VGPR_Count=64, 20ms).
// Topology (proven correct in R17): one 1024-thr WG owns 16 rows x ALL 512
// cols; 16 waves x 2 col-blocks; weights in registers; h / r*h exchanged via
// LDS + __syncthreads (no cross-WG sync at all); xproj prefetch hidden.

#define BB 256
#define TT 512
#define FF 256
#define HH 512
#define HX 1536
#define GROUP_WGS 8
#define LROW 520                     // padded LDS row stride (shorts)

typedef short short8 __attribute__((ext_vector_type(8)));
typedef short short4v __attribute__((ext_vector_type(4)));
typedef float float4v __attribute__((ext_vector_type(4)));
typedef unsigned long long u64;
typedef unsigned short ushort;

// ws layout (bytes)
#define WFRAG_OFF 0
#define WFRAG_BYTES (32 * 3 * 24 * 64 * 8 * 2)            // 2,359,296
#define HBUF_OFF (WFRAG_OFF + WFRAG_BYTES)                 // bf16 h   [256][512]
#define RHBUF_OFF (HBUF_OFF + BB * HH * 2)                 // bf16 r*h [256][512]
#define HFIN_OFF (RHBUF_OFF + BB * HH * 2)                 // f32 h_final
#define CTRL_OFF (HFIN_OFF + BB * HH * 4)                  // claims + done + flags
#define CTRL_BYTES 16384
#define XBASE_OFF (CTRL_OFF + CTRL_BYTES)
#define XB_BYTES ((size_t)BB * TT * FF * 2)                // 67 MB (mode 1)
#define XPROJ_BYTES ((size_t)BB * TT * HX * 2)             // 402 MB (mode 2)
#define WS_M2 ((size_t)XBASE_OFF + XPROJ_BYTES)
#define WS_M1 ((size_t)XBASE_OFF + XB_BYTES)

__device__ __forceinline__ short f2bf(float f) {
  unsigned u = __builtin_bit_cast(unsigned, f);
  u += 0x7fffu + ((u >> 16) & 1u);            // RNE to bf16
  return (short)(u >> 16);
}
__device__ __forceinline__ float bf2f(ushort u) {
  return __builtin_bit_cast(float, (unsigned)u << 16);
}
__device__ __forceinline__ float sigm(float v) { return 1.0f / (1.0f + __expf(-v)); }
__device__ __forceinline__ float tanh_(float v) { return 2.0f / (1.0f + __expf(-2.0f * v)) - 1.0f; }
__device__ __forceinline__ float4v mfma_bf16(short8 a, short8 b, float4v c) {
  return __builtin_amdgcn_mfma_f32_16x16x32_bf16(a, b, c, 0, 0, 0);
}

// ---- weight prep: f32 [768][512] -> bf16 MFMA B-fragments ----
__global__ void prep_w(const float* __restrict__ Wz, const float* __restrict__ Wr,
                       const float* __restrict__ Wh, short* __restrict__ wfrag) {
  int id = blockIdx.x * 256 + threadIdx.x;     // 576*256 == 32*3*24*64
  int lane = id & 63;
  int rest = id >> 6;
  int kk = rest % 24;
  int gc = rest / 24;
  int g = gc % 3;
  int cb = gc / 3;
  if (cb >= 32) return;
  const float* W = (g == 0) ? Wz : ((g == 1) ? Wr : Wh);
  int n = cb * 16 + (lane & 15);
  int kbase = kk * 32 + (lane >> 4) * 8;
  short8 v;
#pragma unroll
  for (int j = 0; j < 8; ++j) v[j] = f2bf(W[(size_t)(kbase + j) * HH + n]);
  *(((short8*)wfrag) + id) = v;
}

// ---- x prep (mode 1 fallback): f32 -> bf16 ----
__global__ void xprep(const float* __restrict__ x, short* __restrict__ xb) {
  size_t i = (size_t)blockIdx.x * 256 + threadIdx.x;
  const float4v* src = (const float4v*)x;
  float4v a = src[i * 2], b = src[i * 2 + 1];
  short8 v;
  v[0] = f2bf(a[0]); v[1] = f2bf(a[1]); v[2] = f2bf(a[2]); v[3] = f2bf(a[3]);
  v[4] = f2bf(b[0]); v[5] = f2bf(b[1]); v[6] = f2bf(b[2]); v[7] = f2bf(b[3]);
  *(((short8*)xb) + i) = v;
}

// ---- xproj GEMM (mode 2): [BT,256] @ x-part weights -> bf16 [BT][3*512], bias folded ----
__global__ __launch_bounds__(256) void xproj_gemm(
    const float* __restrict__ x, const short* __restrict__ wfrag,
    const float* __restrict__ bz, const float* __restrict__ br,
    const float* __restrict__ bh, short* __restrict__ xp) {
  const int w = threadIdx.x >> 6, l = threadIdx.x & 63;
  const int l15 = l & 15, lhi = l >> 4;
  const size_t row0 = (size_t)blockIdx.x * 64 + w * 16;
  const float* xl = x + (row0 + l15) * FF + lhi * 8;
  short8 xf[8];
#pragma unroll
  for (int kx = 0; kx < 8; ++kx) {
    float4v a = *(const float4v*)(xl + kx * 32);
    float4v b2 = *(const float4v*)(xl + kx * 32 + 4);
    short8 v;
    v[0] = f2bf(a[0]); v[1] = f2bf(a[1]); v[2] = f2bf(a[2]); v[3] = f2bf(a[3]);
    v[4] = f2bf(b2[0]); v[5] = f2bf(b2[1]); v[6] = f2bf(b2[2]); v[7] = f2bf(b2[3]);
    xf[kx] = v;
  }
  const short8* wf = (const short8*)wfrag;
#pragma unroll 1
  for (int cb = 0; cb < 32; ++cb) {
#pragma unroll
    for (int g = 0; g < 3; ++g) {
      const float* bias = (g == 0) ? bz : ((g == 1) ? br : bh);
      float bv = bias[cb * 16 + l15];
      float4v acc = {bv, bv, bv, bv};
#pragma unroll
      for (int kx = 0; kx < 8; ++kx)
        acc = mfma_bf16(xf[kx], wf[((cb * 3 + g) * 24 + 16 + kx) * 64 + l], acc);
#pragma unroll
      for (int i = 0; i < 4; ++i)
        xp[(row0 + lhi * 4 + i) * HX + g * 512 + cb * 16 + l15] = f2bf(acc[i]);
    }
  }
}

// =========== single-WG-per-group GRU: 1024 thr, LDS-only exchange ===========
// __launch_bounds__(1024, 4): 16-wave WG at 4 waves/EU == 1 WG/CU ==
// 512-VGPR budget (the 384-reg weight arrays MUST stay in registers).
__global__ __launch_bounds__(1024, 4) void gru1w(
    const short* __restrict__ xp, const short* __restrict__ wfrag,
    float* __restrict__ hfin, int* __restrict__ ctrl) {
  __shared__ short lds[2 * 16 * LROW];   // buf0 = h tile, buf1 = rh tile
  int* done = ctrl + 192;

  if (blockIdx.x >= 16) {
    // burner: keep clocks up; moderate poll cadence
    float a = (float)threadIdx.x;
    for (;;) {
#pragma unroll 64
      for (int i = 0; i < 1024; ++i) a = __builtin_fmaf(a, 1.0000001f, 1.0f);
      asm volatile("" : "+v"(a));
      if (__hip_atomic_load(done, __ATOMIC_RELAXED, __HIP_MEMORY_SCOPE_AGENT) >= 16)
        break;
    }
    asm volatile("" :: "v"(a));
    return;
  }

  const int rb = blockIdx.x * 16;              // this WG's 16 batch rows
  const int tid = threadIdx.x;
  const int wv = tid >> 6;                     // wave 0..15
  const int l = tid & 63, l15 = l & 15, lhi = l >> 4;
  const int cb0 = wv * 2, cb1 = wv * 2 + 1;    // 16-col blocks
  const int c0 = cb0 * 16, c1 = cb1 * 16;      // col bases

  // ---- weights (h-part): 6 x 16 short8 = 384 VGPR ----
  const short8* wf = (const short8*)wfrag;
  short8 wz0[16], wz1[16], wr0[16], wr1[16], wh0[16], wh1[16];
#pragma unroll
  for (int kk = 0; kk < 16; ++kk) {
    wz0[kk] = wf[((cb0 * 3 + 0) * 24 + kk) * 64 + l];
    wz1[kk] = wf[((cb1 * 3 + 0) * 24 + kk) * 64 + l];
    wr0[kk] = wf[((cb0 * 3 + 1) * 24 + kk) * 64 + l];
    wr1[kk] = wf[((cb1 * 3 + 1) * 24 + kk) * 64 + l];
    wh0[kk] = wf[((cb0 * 3 + 2) * 24 + kk) * 64 + l];
    wh1[kk] = wf[((cb1 * 3 + 2) * 24 + kk) * 64 + l];
  }

  // xproj row-base pointers (4 rows this lane accumulates)
  const short* xpp[4];
#pragma unroll
  for (int i = 0; i < 4; ++i)
    xpp[i] = xp + (size_t)(rb + lhi * 4 + i) * TT * HX;

  float4v h0 = {0, 0, 0, 0}, h1 = {0, 0, 0, 0};
  float4v z0, z1;
  ushort nz0[4], nr0[4], nh0[4], nz1[4], nr1[4], nh1[4];

#define DSFRAG(BUF, KK)                                                      \
  (*(const short8*)&lds[(BUF) * 16 * LROW + l15 * LROW + (KK) * 32 + lhi * 8])

  // prologue: h tile = zeros; stage xproj(t=0)
  for (int i = tid; i < 16 * LROW; i += 1024) lds[i] = 0;
#pragma unroll
  for (int i = 0; i < 4; ++i) {
    nz0[i] = *(const ushort*)(xpp[i] + 0 * 512 + c0 + l15);
    nr0[i] = *(const ushort*)(xpp[i] + 1 * 512 + c0 + l15);
    nh0[i] = *(const ushort*)(xpp[i] + 2 * 512 + c0 + l15);
    nz1[i] = *(const ushort*)(xpp[i] + 0 * 512 + c1 + l15);
    nr1[i] = *(const ushort*)(xpp[i] + 1 * 512 + c1 + l15);
    nh1[i] = *(const ushort*)(xpp[i] + 2 * 512 + c1 + l15);
  }
  __syncthreads();

#pragma unroll 1
  for (int t = 0; t < TT; ++t) {
    const bool more = (t + 1 < TT);
    // ===== P1: z,r from h tile (buf0); write rh tile (buf1) =====
    float4v az0, ar0, az1, ar1;
#pragma unroll
    for (int i = 0; i < 4; ++i) {
      az0[i] = bf2f(nz0[i]); ar0[i] = bf2f(nr0[i]);
      az1[i] = bf2f(nz1[i]); ar1[i] = bf2f(nr1[i]);
    }
#pragma unroll
    for (int kk = 0; kk < 16; ++kk) {
      short8 A = DSFRAG(0, kk);
      az0 = mfma_bf16(A, wz0[kk], az0);
      ar0 = mfma_bf16(A, wr0[kk], ar0);
      az1 = mfma_bf16(A, wz1[kk], az1);
      ar1 = mfma_bf16(A, wr1[kk], ar1);
    }
#pragma unroll
    for (int i = 0; i < 4; ++i) {
      z0[i] = sigm(az0[i]);
      z1[i] = sigm(az1[i]);
      float rv0 = sigm(ar0[i]);
      float rv1 = sigm(ar1[i]);
      int row = lhi * 4 + i;
      lds[16 * LROW + row * LROW + c0 + l15] = f2bf(rv0 * h0[i]);
      lds[16 * LROW + row * LROW + c1 + l15] = f2bf(rv1 * h1[i]);
    }
    __syncthreads();

    // ===== P2: h_tilde from rh tile (buf1); update h; write h tile =====
    float4v ah0, ah1;
#pragma unroll
    for (int i = 0; i < 4; ++i) { ah0[i] = bf2f(nh0[i]); ah1[i] = bf2f(nh1[i]); }
    // issue xproj(t+1) prefetch now -- lands during the MFMA loop below
    if (more) {
      size_t toff = (size_t)(t + 1) * HX;
#pragma unroll
      for (int i = 0; i < 4; ++i) {
        nz0[i] = *(const ushort*)(xpp[i] + toff + 0 * 512 + c0 + l15);
        nr0[i] = *(const ushort*)(xpp[i] + toff + 1 * 512 + c0 + l15);
        nh0[i] = *(const ushort*)(xpp[i] + toff + 2 * 512 + c0 + l15);
        nz1[i] = *(const ushort*)(xpp[i] + toff + 0 * 512 + c1 + l15);
        nr1[i] = *(const ushort*)(xpp[i] + toff + 1 * 512 + c1 + l15);
        nh1[i] = *(const ushort*)(xpp[i] + toff + 2 * 512 + c1 + l15);
      }
    }
#pragma unroll
    for (int kk = 0; kk < 16; ++kk) {
      short8 A = DSFRAG(1, kk);
      ah0 = mfma_bf16(A, wh0[kk], ah0);
      ah1 = mfma_bf16(A, wh1[kk], ah1);
    }
#pragma unroll
    for (int i = 0; i < 4; ++i) {
      float hv0 = tanh_(ah0[i]);
      float hv1 = tanh_(ah1[i]);
      h0[i] = (1.0f - z0[i]) * h0[i] + z0[i] * hv0;
      h1[i] = (1.0f - z1[i]) * h1[i] + z1[i] * hv1;
      int row = lhi * 4 + i;
      if (more) {
        lds[row * LROW + c0 + l15] = f2bf(h0[i]);
        lds[row * LROW + c1 + l15] = f2bf(h1[i]);
      } else {
        hfin[(size_t)(rb + row) * HH + c0 + l15] = h0[i];
        hfin[(size_t)(rb + row) * HH + c1 + l15] = h1[i];
      }
    }
    if (more) __syncthreads();
  }

  if (tid == 0)
    __hip_atomic_fetch_add(done, 1, __ATOMIC_RELAXED, __HIP_MEMORY_SCOPE_AGENT);
#undef DSFRAG
}

// ================== fallback (modes 1/0): R8/R14-style kernel ==================
__device__ __forceinline__ void wait_flags(const int* fl, int tgt) {
  const int* p = fl + (threadIdx.x & 31);
  for (;;) {
    int v = __hip_atomic_load(p, __ATOMIC_RELAXED, __HIP_MEMORY_SCOPE_AGENT);
    if (!__any(v < tgt)) break;
  }
}
__device__ __forceinline__ void arrive_flag(int* fl, int wid, int val) {
  asm volatile("s_waitcnt vmcnt(0)" ::: "memory");
  if ((threadIdx.x & 63) == 0)
    __hip_atomic_store(fl + wid, val, __ATOMIC_RELAXED, __HIP_MEMORY_SCOPE_AGENT);
}
__device__ __forceinline__ short8 ld_frag(const short* p) {
  const u64* q = (const u64*)p;
  u64 lo = __hip_atomic_load(q, __ATOMIC_RELAXED, __HIP_MEMORY_SCOPE_AGENT);
  u64 hi = __hip_atomic_load(q + 1, __ATOMIC_RELAXED, __HIP_MEMORY_SCOPE_AGENT);
  short4v l4 = __builtin_bit_cast(short4v, lo);
  short4v h4 = __builtin_bit_cast(short4v, hi);
  return __builtin_shufflevector(l4, h4, 0, 1, 2, 3, 4, 5, 6, 7);
}
__device__ __forceinline__ void gate_phase1(const short* hb_lane,
    const short8* wz, const short8* wr, float4v azx, float4v arx,
    float bz, float br, float4v& z, float4v& rr) {
  short8 a[16];
#pragma unroll
  for (int kk = 0; kk < 16; ++kk) a[kk] = ld_frag(hb_lane + kk * 32);
  float4v az = azx, ar = arx;
#pragma unroll
  for (int kk = 0; kk < 16; ++kk) {
    az = mfma_bf16(a[kk], wz[kk], az);
    ar = mfma_bf16(a[kk], wr[kk], ar);
  }
#pragma unroll
  for (int i = 0; i < 4; ++i) {
    z[i] = sigm(az[i] + bz);
    rr[i] = sigm(ar[i] + br);
  }
}
__device__ __forceinline__ float4v gate_phase2(const short* rh_lane,
    const short8* wh, float4v ahx, float bh, float4v z, float4v h_loc) {
  short8 a[16];
#pragma unroll
  for (int kk = 0; kk < 16; ++kk) a[kk] = ld_frag(rh_lane + kk * 32);
  float4v ah = ahx;
#pragma unroll
  for (int kk = 0; kk < 16; ++kk)
    ah = mfma_bf16(a[kk], wh[kk], ah);
  float4v hn;
#pragma unroll
  for (int i = 0; i < 4; ++i) {
    float hv = tanh_(ah[i] + bh);
    hn[i] = (1.0f - z[i]) * h_loc[i] + z[i] * hv;
  }
  return hn;
}
template <bool XB>
__device__ __forceinline__ void load_xf(short8 (&xf)[8], const short* xb_l,
                                        const float* xf_l, int t) {
#pragma unroll
  for (int kx = 0; kx < 8; ++kx) {
    if constexpr (XB) {
      xf[kx] = *(const short8*)(xb_l + (size_t)t * FF + kx * 32);
    } else {
      const float* xl = xf_l + (size_t)t * FF;
      float4v a = *(const float4v*)(xl + kx * 32);
      float4v b2 = *(const float4v*)(xl + kx * 32 + 4);
      short8 v;
      v[0] = f2bf(a[0]); v[1] = f2bf(a[1]); v[2] = f2bf(a[2]); v[3] = f2bf(a[3]);
      v[4] = f2bf(b2[0]); v[5] = f2bf(b2[1]); v[6] = f2bf(b2[2]); v[7] = f2bf(b2[3]);
      xf[kx] = v;
    }
  }
}
__device__ __forceinline__ void prime_x(const short8 (&xf)[8],
    const short8* wz, const short8* wr, const short8* wh,
    float4v& azx, float4v& arx, float4v& ahx) {
  azx = (float4v){0.f, 0.f, 0.f, 0.f};
  arx = (float4v){0.f, 0.f, 0.f, 0.f};
  ahx = (float4v){0.f, 0.f, 0.f, 0.f};
#pragma unroll
  for (int kx = 0; kx < 8; ++kx) {
    azx = mfma_bf16(xf[kx], wz[16 + kx], azx);
    arx = mfma_bf16(xf[kx], wr[16 + kx], arx);
    ahx = mfma_bf16(xf[kx], wh[16 + kx], ahx);
  }
}
template <int XM>
__global__ __launch_bounds__(256, 1) void gru_kernel(
    const void* __restrict__ xv, const short* __restrict__ wfrag,
    short* __restrict__ hbuf, short* __restrict__ rhbuf,
    float* __restrict__ hfin, int* __restrict__ ctrl,
    const float* __restrict__ bzv, const float* __restrict__ brv,
    const float* __restrict__ bhv) {
  __shared__ int s_slot, s_xcc;
  if (threadIdx.x == 0) {
    unsigned xcc;
    asm volatile("s_getreg_b32 %0, hwreg(HW_REG_XCC_ID)" : "=s"(xcc));
    xcc &= 7u;
    s_xcc = (int)xcc;
    s_slot = atomicAdd(ctrl + xcc * 16, 1);
  }
  __syncthreads();
  const int slot = s_slot;
  if (slot >= GROUP_WGS) return;
  const int group = s_xcc;
  const int member = slot;
  const int tid = threadIdx.x;
  const int w = tid >> 6;
  const int l = tid & 63;
  const int l15 = l & 15;
  const int lhi = l >> 4;
  const int cbg = member * 4 + w;
  const int jc = cbg * 16;
  const int rbA = group * 32;
  const int rbB = rbA + 16;
  const short8* wf = (const short8*)wfrag;
  short8 wz[24], wr[24], wh[24];
#pragma unroll
  for (int kk = 0; kk < 24; ++kk) wz[kk] = wf[((cbg * 3 + 0) * 24 + kk) * 64 + l];
#pragma unroll
  for (int kk = 0; kk < 24; ++kk) wr[kk] = wf[((cbg * 3 + 1) * 24 + kk) * 64 + l];
#pragma unroll
  for (int kk = 0; kk < 24; ++kk) wh[kk] = wf[((cbg * 3 + 2) * 24 + kk) * 64 + l];
  const float bz = bzv[jc + l15], br = brv[jc + l15], bh = bhv[jc + l15];
  const int drowA = rbA + lhi * 4, drowB = rbB + lhi * 4;
  const int dcol = jc + l15;
  const short* hbA = hbuf + (size_t)(rbA + l15) * HH + lhi * 8;
  const short* hbB = hbuf + (size_t)(rbB + l15) * HH + lhi * 8;
  const short* rhA = rhbuf + (size_t)(rbA + l15) * HH + lhi * 8;
  const short* rhB = rhbuf + (size_t)(rbB + l15) * HH + lhi * 8;
  const float* xfA32 = (XM == 0) ? ((const float*)xv + (size_t)(rbA + l15) * TT * FF + lhi * 8) : nullptr;
  const float* xfB32 = (XM == 0) ? ((const float*)xv + (size_t)(rbB + l15) * TT * FF + lhi * 8) : nullptr;
  const short* xbA = (XM == 1) ? ((const short*)xv + (size_t)(rbA + l15) * TT * FF + lhi * 8) : nullptr;
  const short* xbB = (XM == 1) ? ((const short*)xv + (size_t)(rbB + l15) * TT * FF + lhi * 8) : nullptr;
  float4v h_locA = {0.f, 0.f, 0.f, 0.f}, h_locB = {0.f, 0.f, 0.f, 0.f};
  int* fb = ctrl + 256 + 1024 + group * 256;
  int* rhAf = fb, * rhBf = fb + 32, * hAf = fb + 64, * hBf = fb + 96;
  float4v azxA, arxA, ahxA, azxB, arxB, ahxB;
  {
    short8 xf[8];
    load_xf<XM == 1>(xf, xbA, xfA32, 0);
    prime_x(xf, wz, wr, wh, azxA, arxA, ahxA);
    load_xf<XM == 1>(xf, xbB, xfB32, 0);
    prime_x(xf, wz, wr, wh, azxB, arxB, ahxB);
  }
#pragma unroll 1
  for (int t = 0; t < TT; ++t) {
    if (t) wait_flags(hAf, t);
    float4v zA, rrA;
    gate_phase1(hbA, wz, wr, azxA, arxA, bz, br, zA, rrA);
#pragma unroll
    for (int i = 0; i < 4; ++i)
      rhbuf[(size_t)(drowA + i) * HH + dcol] = f2bf(rrA[i] * h_locA[i]);
    arrive_flag(rhAf, cbg, t + 1);
    if (t) wait_flags(hBf, t);
    float4v zB, rrB;
    gate_phase1(hbB, wz, wr, azxB, arxB, bz, br, zB, rrB);
#pragma unroll
    for (int i = 0; i < 4; ++i)
      rhbuf[(size_t)(drowB + i) * HH + dcol] = f2bf(rrB[i] * h_locB[i]);
    arrive_flag(rhBf, cbg, t + 1);
    wait_flags(rhAf, t + 1);
    h_locA = gate_phase2(rhA, wh, ahxA, bh, zA, h_locA);
    if (t + 1 < TT) {
#pragma unroll
      for (int i = 0; i < 4; ++i)
        hbuf[(size_t)(drowA + i) * HH + dcol] = f2bf(h_locA[i]);
      arrive_flag(hAf, cbg, t + 1);
    } else {
#pragma unroll
      for (int i = 0; i < 4; ++i)
        hfin[(size_t)(drowA + i) * HH + dcol] = h_locA[i];
    }
    wait_flags(rhBf, t + 1);
    h_locB = gate_phase2(rhB, wh, ahxB, bh, zB, h_locB);
    if (t + 1 < TT) {
#pragma unroll
      for (int i = 0; i < 4; ++i)
        hbuf[(size_t)(drowB + i) * HH + dcol] = f2bf(h_locB[i]);
      arrive_flag(hBf, cbg, t + 1);
    } else {
#pragma unroll
      for (int i = 0; i < 4; ++i)
        hfin[(size_t)(drowB + i) * HH + dcol] = h_locB[i];
    }
    if (t + 1 < TT) {
      short8 xf[8];
      load_xf<XM == 1>(xf, xbA, xfA32, t + 1);
      prime_x(xf, wz, wr, wh, azxA, arxA, ahxA);
      load_xf<XM == 1>(xf, xbB, xfB32, t + 1);
      prime_x(xf, wz, wr, wh, azxB, arxB, ahxB);
    }
  }
}

// out[b, c] = h_final[b,:] @ fc_w[:,c] + fc_b[c]
__global__ void fc_kernel(const float* __restrict__ hfin, const float* __restrict__ fw,
                          const float* __restrict__ fb, float* __restrict__ out) {
  int b = blockIdx.x;
  int tid = threadIdx.x;  // 64
  float p[10];
#pragma unroll
  for (int c = 0; c < 10; ++c) p[c] = 0.f;
  for (int k = tid; k < HH; k += 64) {
    float hv = hfin[(size_t)b * HH + k];
#pragma unroll
    for (int c = 0; c < 10; ++c) p[c] += hv * fw[k * 10 + c];
  }
#pragma unroll
  for (int c = 0; c < 10; ++c) {
    float v = p[c];
    for (int off = 32; off > 0; off >>= 1) v += __shfl_down(v, off);
    if (tid == 0) out[b * 10 + c] = v + fb[c];
  }
}

extern "C" void kernel_launch(void* const* d_in, const int* in_sizes, int n_in,
                              void* d_out, int out_size, void* d_ws, size_t ws_size,
                              hipStream_t stream) {
  const float* x = (const float*)d_in[0];
  const float* Wz_w = (const float*)d_in[1];
  const float* Wz_b = (const float*)d_in[2];
  const float* Wr_w = (const float*)d_in[3];
  const float* Wr_b = (const float*)d_in[4];
  const float* Wh_w = (const float*)d_in[5];
  const float* Wh_b = (const float*)d_in[6];
  const float* fc_w = (const float*)d_in[7];
  const float* fc_b = (const float*)d_in[8];

  char* ws = (char*)d_ws;
  short* wfrag = (short*)(ws + WFRAG_OFF);
  short* hbuf = (short*)(ws + HBUF_OFF);
  short* rhbuf = (short*)(ws + RHBUF_OFF);
  float* hfin = (float*)(ws + HFIN_OFF);
  int* ctrl = (int*)(ws + CTRL_OFF);
  short* xbase = (short*)(ws + XBASE_OFF);

  // h0 = 0 (mode 1/0 path), ctrl (claims + done) = 0 (EVERY launch)
  hipMemsetAsync(hbuf, 0, BB * HH * 2, stream);
  hipMemsetAsync(ctrl, 0, CTRL_BYTES, stream);

  prep_w<<<576, 256, 0, stream>>>(Wz_w, Wr_w, Wh_w, wfrag);

  if (ws_size >= WS_M2) {
    xproj_gemm<<<BB * TT / 64, 256, 0, stream>>>(x, wfrag, Wz_b, Wr_b, Wh_b, xbase);
    gru1w<<<144, 1024, 0, stream>>>(xbase, wfrag, hfin, ctrl);
  } else if (ws_size >= WS_M1) {
    xprep<<<(BB * TT * FF / 8) / 256, 256, 0, stream>>>(x, xbase);
    gru_kernel<1><<<256, 256, 0, stream>>>(xbase, wfrag, hbuf, rhbuf, hfin, ctrl,
                                           Wz_b, Wr_b, Wh_b);
  } else {
    gru_kernel<0><<<256, 256, 0, stream>>>(x, wfrag, hbuf, rhbuf, hfin, ctrl,
                                           Wz_b, Wr_b, Wh_b);
  }
  fc_kernel<<<BB, 64, 0, stream>>>(hfin, fc_w, fc_b, (float*)d_out);
}

// Round 19
// 2645.152 us; speedup vs baseline: 7.7165x; 7.7147x over previous
//
#include <hip/hip_runtime.h>

// GRU: B=256, T=512, F=256, H=512, C=10  (MI355X / gfx950)
// Round 19 = Round 14 verbatim (best measured: 2642us). Lines closed by
// experiment: sc0 coherence bypass (R6/R7/R16: crash/hang/4x-regression),
// single-WG register-resident weights (R17/R18: compiler caps VGPR at 64
// for 16-wave WGs -> full spill), schedule variants around the 2-phase
// structure (R10/R12/R13: all lost to R14). Structure: 16 XCD-local groups
// x 8 WGs x 16 rows, one row-set per WG, 2 agent-scope exchange phases per
// step (~2.3us each, LIC round-trip bound); LDS tile staging; per-wave flag
// barriers (arrive-before-wait, own-slot skip); loud burner WGs hold DPM
// clocks; xproj precomputed by parallel GEMM (bias folded).

#define BB 256
#define TT 512
#define FF 256
#define HH 512
#define HX 1536
#define GROUP_WGS 8
#define NGRP 16

typedef short short8 __attribute__((ext_vector_type(8)));
typedef short short4v __attribute__((ext_vector_type(4)));
typedef float float4v __attribute__((ext_vector_type(4)));
typedef unsigned long long u64;
typedef unsigned short ushort;

// ws layout (bytes)
#define WFRAG_OFF 0
#define WFRAG_BYTES (32 * 3 * 24 * 64 * 8 * 2)            // 2,359,296
#define HBUF_OFF (WFRAG_OFF + WFRAG_BYTES)                 // bf16 h   [256][512]
#define RHBUF_OFF (HBUF_OFF + BB * HH * 2)                 // bf16 r*h [256][512]
#define HFIN_OFF (RHBUF_OFF + BB * HH * 2)                 // f32 h_final
#define CTRL_OFF (HFIN_OFF + BB * HH * 4)                  // claims + done + flags
#define CTRL_BYTES 16384
#define XBASE_OFF (CTRL_OFF + CTRL_BYTES)
#define XB_BYTES ((size_t)BB * TT * FF * 2)                // 67 MB (mode 1)
#define XPROJ_BYTES ((size_t)BB * TT * HX * 2)             // 402 MB (mode 2)
#define WS_M2 ((size_t)XBASE_OFF + XPROJ_BYTES)
#define WS_M1 ((size_t)XBASE_OFF + XB_BYTES)

__device__ __forceinline__ short f2bf(float f) {
  unsigned u = __builtin_bit_cast(unsigned, f);
  u += 0x7fffu + ((u >> 16) & 1u);            // RNE to bf16
  return (short)(u >> 16);
}
__device__ __forceinline__ float bf2f(ushort u) {
  return __builtin_bit_cast(float, (unsigned)u << 16);
}
__device__ __forceinline__ float sigm(float v) { return 1.0f / (1.0f + __expf(-v)); }
__device__ __forceinline__ float tanh_(float v) { return 2.0f / (1.0f + __expf(-2.0f * v)) - 1.0f; }
__device__ __forceinline__ float4v mfma_bf16(short8 a, short8 b, float4v c) {
  return __builtin_amdgcn_mfma_f32_16x16x32_bf16(a, b, c, 0, 0, 0);
}

// ---- weight prep: f32 [768][512] -> bf16 MFMA B-fragments ----
__global__ void prep_w(const float* __restrict__ Wz, const float* __restrict__ Wr,
                       const float* __restrict__ Wh, short* __restrict__ wfrag) {
  int id = blockIdx.x * 256 + threadIdx.x;     // 576*256 == 32*3*24*64
  int lane = id & 63;
  int rest = id >> 6;
  int kk = rest % 24;
  int gc = rest / 24;
  int g = gc % 3;
  int cb = gc / 3;
  if (cb >= 32) return;
  const float* W = (g == 0) ? Wz : ((g == 1) ? Wr : Wh);
  int n = cb * 16 + (lane & 15);
  int kbase = kk * 32 + (lane >> 4) * 8;
  short8 v;
#pragma unroll
  for (int j = 0; j < 8; ++j) v[j] = f2bf(W[(size_t)(kbase + j) * HH + n]);
  *(((short8*)wfrag) + id) = v;
}

// ---- x prep (mode 1 fallback): f32 -> bf16 ----
__global__ void xprep(const float* __restrict__ x, short* __restrict__ xb) {
  size_t i = (size_t)blockIdx.x * 256 + threadIdx.x;
  const float4v* src = (const float4v*)x;
  float4v a = src[i * 2], b = src[i * 2 + 1];
  short8 v;
  v[0] = f2bf(a[0]); v[1] = f2bf(a[1]); v[2] = f2bf(a[2]); v[3] = f2bf(a[3]);
  v[4] = f2bf(b[0]); v[5] = f2bf(b[1]); v[6] = f2bf(b[2]); v[7] = f2bf(b[3]);
  *(((short8*)xb) + i) = v;
}

// ---- xproj GEMM (mode 2): [BT,256] @ x-part weights -> bf16 [BT][3*512], bias folded ----
__global__ __launch_bounds__(256) void xproj_gemm(
    const float* __restrict__ x, const short* __restrict__ wfrag,
    const float* __restrict__ bz, const float* __restrict__ br,
    const float* __restrict__ bh, short* __restrict__ xp) {
  const int w = threadIdx.x >> 6, l = threadIdx.x & 63;
  const int l15 = l & 15, lhi = l >> 4;
  const size_t row0 = (size_t)blockIdx.x * 64 + w * 16;
  const float* xl = x + (row0 + l15) * FF + lhi * 8;
  short8 xf[8];
#pragma unroll
  for (int kx = 0; kx < 8; ++kx) {
    float4v a = *(const float4v*)(xl + kx * 32);
    float4v b2 = *(const float4v*)(xl + kx * 32 + 4);
    short8 v;
    v[0] = f2bf(a[0]); v[1] = f2bf(a[1]); v[2] = f2bf(a[2]); v[3] = f2bf(a[3]);
    v[4] = f2bf(b2[0]); v[5] = f2bf(b2[1]); v[6] = f2bf(b2[2]); v[7] = f2bf(b2[3]);
    xf[kx] = v;
  }
  const short8* wf = (const short8*)wfrag;
#pragma unroll 1
  for (int cb = 0; cb < 32; ++cb) {
#pragma unroll
    for (int g = 0; g < 3; ++g) {
      const float* bias = (g == 0) ? bz : ((g == 1) ? br : bh);
      float bv = bias[cb * 16 + l15];
      float4v acc = {bv, bv, bv, bv};
#pragma unroll
      for (int kx = 0; kx < 8; ++kx)
        acc = mfma_bf16(xf[kx], wf[((cb * 3 + g) * 24 + 16 + kx) * 64 + l], acc);
#pragma unroll
      for (int i = 0; i < 4; ++i)
        xp[(row0 + lhi * 4 + i) * HX + g * 512 + cb * 16 + l15] = f2bf(acc[i]);
    }
  }
}

// ---- flag primitives ----
// wait for all 32 wave-flags >= tgt, skipping our own slot (set just before)
__device__ __forceinline__ void wait_all(const int* fl, int tgt, int own) {
  const int li = threadIdx.x & 31;
  const int* p = fl + li;
  const bool self = (li == own);
  int tries = 0;
  for (;;) {
    int v = self ? tgt
                 : __hip_atomic_load(p, __ATOMIC_RELAXED, __HIP_MEMORY_SCOPE_AGENT);
    if (!__any(v < tgt)) break;
    if (++tries > 64) __builtin_amdgcn_s_sleep(1);
  }
}

// L1-bypassing 16B fragment load (two relaxed agent-scope u64 loads)
__device__ __forceinline__ short8 ld_frag(const short* p) {
  const u64* q = (const u64*)p;
  u64 lo = __hip_atomic_load(q, __ATOMIC_RELAXED, __HIP_MEMORY_SCOPE_AGENT);
  u64 hi = __hip_atomic_load(q + 1, __ATOMIC_RELAXED, __HIP_MEMORY_SCOPE_AGENT);
  short4v l4 = __builtin_bit_cast(short4v, lo);
  short4v h4 = __builtin_bit_cast(short4v, hi);
  return __builtin_shufflevector(l4, h4, 0, 1, 2, 3, 4, 5, 6, 7);
}

// ========= 1-set 2-phase XCD-local GRU, 16 groups (mode 2) =========
__global__ __launch_bounds__(256, 1) void gru1s(
    const short* __restrict__ xp, const short* __restrict__ wfrag,
    short* __restrict__ hbuf, short* __restrict__ rhbuf,
    float* __restrict__ hfin, int* __restrict__ ctrl) {
  __shared__ short lds[2 * 8192];   // buf0 = h tile, buf1 = rh tile
  __shared__ int s_slot, s_xcc;
  if (threadIdx.x == 0) {
    unsigned xcc;
    asm volatile("s_getreg_b32 %0, hwreg(HW_REG_XCC_ID)" : "=s"(xcc));
    xcc &= 7u;
    s_xcc = (int)xcc;
    s_slot = atomicAdd(ctrl + xcc * 16, 1);
  }
  __syncthreads();
  const int slot = s_slot;
  int* done = ctrl + 192;

  if (slot >= 2 * GROUP_WGS) {
    // burner (R9 loud cadence -- fastest measured)
    float a = (float)threadIdx.x;
    for (;;) {
#pragma unroll
      for (int i = 0; i < 512; ++i) a = __builtin_fmaf(a, 1.0000001f, 1.0f);
      asm volatile("" : "+v"(a));
      if (__hip_atomic_load(done, __ATOMIC_RELAXED, __HIP_MEMORY_SCOPE_AGENT) >= NGRP)
        break;
    }
    asm volatile("" :: "v"(a));
    return;
  }

  const int group = s_xcc * 2 + (slot >> 3);   // 0..15, XCD-local
  const int member = slot & 7;
  const int tid = threadIdx.x;
  const int w = tid >> 6, l = tid & 63, l15 = l & 15, lhi = l >> 4;
  const int cbg = member * 4 + w, jc = cbg * 16;
  const int rb = group * 16;                   // 16 rows per group
  const int dcol = jc + l15;

  // ---- weights (h-part) -> registers (192 VGPR) ----
  const short8* wf = (const short8*)wfrag;
  short8 wz[16], wr[16], wh[16];
#pragma unroll
  for (int kk = 0; kk < 16; ++kk) wz[kk] = wf[((cbg * 3 + 0) * 24 + kk) * 64 + l];
#pragma unroll
  for (int kk = 0; kk < 16; ++kk) wr[kk] = wf[((cbg * 3 + 1) * 24 + kk) * 64 + l];
#pragma unroll
  for (int kk = 0; kk < 16; ++kk) wh[kk] = wf[((cbg * 3 + 2) * 24 + kk) * 64 + l];

  const short* hS = hbuf + (size_t)rb * HH;    // 16KB tile bases
  const short* rhS = rhbuf + (size_t)rb * HH;

  const short* xpp[4];
#pragma unroll
  for (int i = 0; i < 4; ++i)
    xpp[i] = xp + (size_t)(rb + lhi * 4 + i) * TT * HX + dcol;

  int* fb = ctrl + 256 + group * 64;
  int* rhF = fb, * hF = fb + 32;

  float4v h_loc = {0, 0, 0, 0};
  float4v z;
  ushort nz[4], nr[4], nh[4];
  short8 Ra[4];

#define ACK asm volatile("s_waitcnt vmcnt(0)" ::: "memory")
#define ARR(FL, VAL)                                                         \
  { if (l == 0) __hip_atomic_store((FL) + cbg, VAL, __ATOMIC_RELAXED,        \
                                   __HIP_MEMORY_SCOPE_AGENT); }
#define DSW(BUF, R)                                                          \
  { _Pragma("unroll") for (int i_ = 0; i_ < 4; ++i_) {                       \
      int idx_ = w * 2048 + i_ * 512 + l * 8;                                \
      idx_ ^= ((w * 4 + i_) & 7) << 3;                                       \
      *(short8*)&lds[(BUF) * 8192 + idx_] = (R)[i_]; } }
#define LDG(R, GSRC)                                                         \
  { _Pragma("unroll") for (int i_ = 0; i_ < 4; ++i_)                         \
      (R)[i_] = ld_frag((GSRC) + w * 2048 + i_ * 512 + l * 8); }
#define DSFRAG(BUF, KK)                                                      \
  (*(const short8*)&lds[(BUF) * 8192 +                                       \
      (((l15 << 9) | ((KK) * 32 + lhi * 8)) ^ ((l15 & 7) << 3))])

  // prologue: buf0 = h(t=0) = zeros; xproj(t=0) staged
  for (int i = tid; i < 8192; i += 256) lds[i] = 0;
#pragma unroll
  for (int i = 0; i < 4; ++i) {
    nz[i] = *(const ushort*)(xpp[i]);
    nr[i] = *(const ushort*)(xpp[i] + 512);
    nh[i] = *(const ushort*)(xpp[i] + 1024);
  }

#pragma unroll 1
  for (int t = 0; t < TT; ++t) {
    const bool more = (t + 1 < TT);
    // ===== P1: consume buf0 (h), produce rh =====
    __syncthreads();                 // buf0 ready (prev P2's DSW / prologue)
    {
      float4v az, ar;
#pragma unroll
      for (int i = 0; i < 4; ++i) { az[i] = bf2f(nz[i]); ar[i] = bf2f(nr[i]); }
#pragma unroll
      for (int kk = 0; kk < 16; ++kk) {
        short8 a_ = DSFRAG(0, kk);
        az = mfma_bf16(a_, wz[kk], az);
        ar = mfma_bf16(a_, wr[kk], ar);
      }
#pragma unroll
      for (int i = 0; i < 4; ++i) {
        z[i] = sigm(az[i]);
        float rv = sigm(ar[i]);
        rhbuf[(size_t)(rb + lhi * 4 + i) * HH + dcol] = f2bf(rv * h_loc[i]);
      }
    }
    ACK;                             // rh stores acked at coherence point
    ARR(rhF, t + 1);
    wait_all(rhF, t + 1, cbg);       // all 32 waves' rh visible
    LDG(Ra, rhS);                    // full rh tile -> regs
    DSW(1, Ra);                      // -> buf1 (stalls on load return)

    // ===== P2: consume buf1 (rh), produce h =====
    __syncthreads();
    {
      float4v ah;
#pragma unroll
      for (int i = 0; i < 4; ++i) ah[i] = bf2f(nh[i]);
#pragma unroll
      for (int kk = 0; kk < 16; ++kk)
        ah = mfma_bf16(DSFRAG(1, kk), wh[kk], ah);
#pragma unroll
      for (int i = 0; i < 4; ++i) {
        float hv = tanh_(ah[i]);
        h_loc[i] = (1.0f - z[i]) * h_loc[i] + z[i] * hv;
        size_t dr = (size_t)(rb + lhi * 4 + i) * HH + dcol;
        if (more) hbuf[dr] = f2bf(h_loc[i]);
        else hfin[dr] = h_loc[i];
      }
    }
    if (more) {
      ACK;
      ARR(hF, t + 1);
      // xproj(t+1) prefetch: lands inside the wait, never stalls an ACK
      {
        size_t toff = (size_t)(t + 1) * HX;
#pragma unroll
        for (int i = 0; i < 4; ++i) {
          nz[i] = *(const ushort*)(xpp[i] + toff);
          nr[i] = *(const ushort*)(xpp[i] + toff + 512);
          nh[i] = *(const ushort*)(xpp[i] + toff + 1024);
        }
      }
      wait_all(hF, t + 1, cbg);
      LDG(Ra, hS);
      DSW(0, Ra);
    }
  }

  if (member == 0 && tid == 0)
    __hip_atomic_fetch_add(done, 1, __ATOMIC_RELAXED, __HIP_MEMORY_SCOPE_AGENT);
#undef ACK
#undef ARR
#undef DSW
#undef LDG
#undef DSFRAG
}

// ================== fallback (modes 1/0): R8 kernel ==================
__device__ __forceinline__ void wait_flags(const int* fl, int tgt) {
  const int* p = fl + (threadIdx.x & 31);
  for (;;) {
    int v = __hip_atomic_load(p, __ATOMIC_RELAXED, __HIP_MEMORY_SCOPE_AGENT);
    if (!__any(v < tgt)) break;
  }
}
__device__ __forceinline__ void arrive_flag(int* fl, int wid, int val) {
  asm volatile("s_waitcnt vmcnt(0)" ::: "memory");
  if ((threadIdx.x & 63) == 0)
    __hip_atomic_store(fl + wid, val, __ATOMIC_RELAXED, __HIP_MEMORY_SCOPE_AGENT);
}
__device__ __forceinline__ void gate_phase1(const short* hb_lane,
    const short8* wz, const short8* wr, float4v azx, float4v arx,
    float bz, float br, float4v& z, float4v& rr) {
  short8 a[16];
#pragma unroll
  for (int kk = 0; kk < 16; ++kk) a[kk] = ld_frag(hb_lane + kk * 32);
  float4v az = azx, ar = arx;
#pragma unroll
  for (int kk = 0; kk < 16; ++kk) {
    az = mfma_bf16(a[kk], wz[kk], az);
    ar = mfma_bf16(a[kk], wr[kk], ar);
  }
#pragma unroll
  for (int i = 0; i < 4; ++i) {
    z[i] = sigm(az[i] + bz);
    rr[i] = sigm(ar[i] + br);
  }
}
__device__ __forceinline__ float4v gate_phase2(const short* rh_lane,
    const short8* wh, float4v ahx, float bh, float4v z, float4v h_loc) {
  short8 a[16];
#pragma unroll
  for (int kk = 0; kk < 16; ++kk) a[kk] = ld_frag(rh_lane + kk * 32);
  float4v ah = ahx;
#pragma unroll
  for (int kk = 0; kk < 16; ++kk)
    ah = mfma_bf16(a[kk], wh[kk], ah);
  float4v hn;
#pragma unroll
  for (int i = 0; i < 4; ++i) {
    float hv = tanh_(ah[i] + bh);
    hn[i] = (1.0f - z[i]) * h_loc[i] + z[i] * hv;
  }
  return hn;
}
template <bool XB>
__device__ __forceinline__ void load_xf(short8 (&xf)[8], const short* xb_l,
                                        const float* xf_l, int t) {
#pragma unroll
  for (int kx = 0; kx < 8; ++kx) {
    if constexpr (XB) {
      xf[kx] = *(const short8*)(xb_l + (size_t)t * FF + kx * 32);
    } else {
      const float* xl = xf_l + (size_t)t * FF;
      float4v a = *(const float4v*)(xl + kx * 32);
      float4v b2 = *(const float4v*)(xl + kx * 32 + 4);
      short8 v;
      v[0] = f2bf(a[0]); v[1] = f2bf(a[1]); v[2] = f2bf(a[2]); v[3] = f2bf(a[3]);
      v[4] = f2bf(b2[0]); v[5] = f2bf(b2[1]); v[6] = f2bf(b2[2]); v[7] = f2bf(b2[3]);
      xf[kx] = v;
    }
  }
}
__device__ __forceinline__ void prime_x(const short8 (&xf)[8],
    const short8* wz, const short8* wr, const short8* wh,
    float4v& azx, float4v& arx, float4v& ahx) {
  azx = (float4v){0.f, 0.f, 0.f, 0.f};
  arx = (float4v){0.f, 0.f, 0.f, 0.f};
  ahx = (float4v){0.f, 0.f, 0.f, 0.f};
#pragma unroll
  for (int kx = 0; kx < 8; ++kx) {
    azx = mfma_bf16(xf[kx], wz[16 + kx], azx);
    arx = mfma_bf16(xf[kx], wr[16 + kx], arx);
    ahx = mfma_bf16(xf[kx], wh[16 + kx], ahx);
  }
}
template <int XM>
__global__ __launch_bounds__(256, 1) void gru_kernel(
    const void* __restrict__ xv, const short* __restrict__ wfrag,
    short* __restrict__ hbuf, short* __restrict__ rhbuf,
    float* __restrict__ hfin, int* __restrict__ ctrl,
    const float* __restrict__ bzv, const float* __restrict__ brv,
    const float* __restrict__ bhv) {
  __shared__ int s_slot, s_xcc;
  if (threadIdx.x == 0) {
    unsigned xcc;
    asm volatile("s_getreg_b32 %0, hwreg(HW_REG_XCC_ID)" : "=s"(xcc));
    xcc &= 7u;
    s_xcc = (int)xcc;
    s_slot = atomicAdd(ctrl + xcc * 16, 1);
  }
  __syncthreads();
  const int slot = s_slot;
  if (slot >= GROUP_WGS) return;
  const int group = s_xcc;
  const int member = slot;
  const int tid = threadIdx.x;
  const int w = tid >> 6;
  const int l = tid & 63;
  const int l15 = l & 15;
  const int lhi = l >> 4;
  const int cbg = member * 4 + w;
  const int jc = cbg * 16;
  const int rbA = group * 32;
  const int rbB = rbA + 16;
  const short8* wf = (const short8*)wfrag;
  short8 wz[24], wr[24], wh[24];
#pragma unroll
  for (int kk = 0; kk < 24; ++kk) wz[kk] = wf[((cbg * 3 + 0) * 24 + kk) * 64 + l];
#pragma unroll
  for (int kk = 0; kk < 24; ++kk) wr[kk] = wf[((cbg * 3 + 1) * 24 + kk) * 64 + l];
#pragma unroll
  for (int kk = 0; kk < 24; ++kk) wh[kk] = wf[((cbg * 3 + 2) * 24 + kk) * 64 + l];
  const float bz = bzv[jc + l15], br = brv[jc + l15], bh = bhv[jc + l15];
  const int drowA = rbA + lhi * 4, drowB = rbB + lhi * 4;
  const int dcol = jc + l15;
  const short* hbA = hbuf + (size_t)(rbA + l15) * HH + lhi * 8;
  const short* hbB = hbuf + (size_t)(rbB + l15) * HH + lhi * 8;
  const short* rhA = rhbuf + (size_t)(rbA + l15) * HH + lhi * 8;
  const short* rhB = rhbuf + (size_t)(rbB + l15) * HH + lhi * 8;
  const float* xfA32 = (XM == 0) ? ((const float*)xv + (size_t)(rbA + l15) * TT * FF + lhi * 8) : nullptr;
  const float* xfB32 = (XM == 0) ? ((const float*)xv + (size_t)(rbB + l15) * TT * FF + lhi * 8) : nullptr;
  const short* xbA = (XM == 1) ? ((const short*)xv + (size_t)(rbA + l15) * TT * FF + lhi * 8) : nullptr;
  const short* xbB = (XM == 1) ? ((const short*)xv + (size_t)(rbB + l15) * TT * FF + lhi * 8) : nullptr;
  float4v h_locA = {0.f, 0.f, 0.f, 0.f}, h_locB = {0.f, 0.f, 0.f, 0.f};
  int* fb = ctrl + 256 + 1024 + group * 256;
  int* rhAf = fb, * rhBf = fb + 32, * hAf = fb + 64, * hBf = fb + 96;
  float4v azxA, arxA, ahxA, azxB, arxB, ahxB;
  {
    short8 xf[8];
    load_xf<XM == 1>(xf, xbA, xfA32, 0);
    prime_x(xf, wz, wr, wh, azxA, arxA, ahxA);
    load_xf<XM == 1>(xf, xbB, xfB32, 0);
    prime_x(xf, wz, wr, wh, azxB, arxB, ahxB);
  }
#pragma unroll 1
  for (int t = 0; t < TT; ++t) {
    if (t) wait_flags(hAf, t);
    float4v zA, rrA;
    gate_phase1(hbA, wz, wr, azxA, arxA, bz, br, zA, rrA);
#pragma unroll
    for (int i = 0; i < 4; ++i)
      rhbuf[(size_t)(drowA + i) * HH + dcol] = f2bf(rrA[i] * h_locA[i]);
    arrive_flag(rhAf, cbg, t + 1);
    if (t) wait_flags(hBf, t);
    float4v zB, rrB;
    gate_phase1(hbB, wz, wr, azxB, arxB, bz, br, zB, rrB);
#pragma unroll
    for (int i = 0; i < 4; ++i)
      rhbuf[(size_t)(drowB + i) * HH + dcol] = f2bf(rrB[i] * h_locB[i]);
    arrive_flag(rhBf, cbg, t + 1);
    wait_flags(rhAf, t + 1);
    h_locA = gate_phase2(rhA, wh, ahxA, bh, zA, h_locA);
    if (t + 1 < TT) {
#pragma unroll
      for (int i = 0; i < 4; ++i)
        hbuf[(size_t)(drowA + i) * HH + dcol] = f2bf(h_locA[i]);
      arrive_flag(hAf, cbg, t + 1);
    } else {
#pragma unroll
      for (int i = 0; i < 4; ++i)
        hfin[(size_t)(drowA + i) * HH + dcol] = h_locA[i];
    }
    wait_flags(rhBf, t + 1);
    h_locB = gate_phase2(rhB, wh, ahxB, bh, zB, h_locB);
    if (t + 1 < TT) {
#pragma unroll
      for (int i = 0; i < 4; ++i)
        hbuf[(size_t)(drowB + i) * HH + dcol] = f2bf(h_locB[i]);
      arrive_flag(hBf, cbg, t + 1);
    } else {
#pragma unroll
      for (int i = 0; i < 4; ++i)
        hfin[(size_t)(drowB + i) * HH + dcol] = h_locB[i];
    }
    if (t + 1 < TT) {
      short8 xf[8];
      load_xf<XM == 1>(xf, xbA, xfA32, t + 1);
      prime_x(xf, wz, wr, wh, azxA, arxA, ahxA);
      load_xf<XM == 1>(xf, xbB, xfB32, t + 1);
      prime_x(xf, wz, wr, wh, azxB, arxB, ahxB);
    }
  }
}

// out[b, c] = h_final[b,:] @ fc_w[:,c] + fc_b[c]
__global__ void fc_kernel(const float* __restrict__ hfin, const float* __restrict__ fw,
                          const float* __restrict__ fb, float* __restrict__ out) {
  int b = blockIdx.x;
  int tid = threadIdx.x;  // 64
  float p[10];
#pragma unroll
  for (int c = 0; c < 10; ++c) p[c] = 0.f;
  for (int k = tid; k < HH; k += 64) {
    float hv = hfin[(size_t)b * HH + k];
#pragma unroll
    for (int c = 0; c < 10; ++c) p[c] += hv * fw[k * 10 + c];
  }
#pragma unroll
  for (int c = 0; c < 10; ++c) {
    float v = p[c];
    for (int off = 32; off > 0; off >>= 1) v += __shfl_down(v, off);
    if (tid == 0) out[b * 10 + c] = v + fb[c];
  }
}

extern "C" void kernel_launch(void* const* d_in, const int* in_sizes, int n_in,
                              void* d_out, int out_size, void* d_ws, size_t ws_size,
                              hipStream_t stream) {
  const float* x = (const float*)d_in[0];
  const float* Wz_w = (const float*)d_in[1];
  const float* Wz_b = (const float*)d_in[2];
  const float* Wr_w = (const float*)d_in[3];
  const float* Wr_b = (const float*)d_in[4];
  const float* Wh_w = (const float*)d_in[5];
  const float* Wh_b = (const float*)d_in[6];
  const float* fc_w = (const float*)d_in[7];
  const float* fc_b = (const float*)d_in[8];

  char* ws = (char*)d_ws;
  short* wfrag = (short*)(ws + WFRAG_OFF);
  short* hbuf = (short*)(ws + HBUF_OFF);
  short* rhbuf = (short*)(ws + RHBUF_OFF);
  float* hfin = (float*)(ws + HFIN_OFF);
  int* ctrl = (int*)(ws + CTRL_OFF);
  short* xbase = (short*)(ws + XBASE_OFF);

  // h0 = 0, claim + done + flag arrays = 0 (EVERY launch)
  hipMemsetAsync(hbuf, 0, BB * HH * 2, stream);
  hipMemsetAsync(ctrl, 0, CTRL_BYTES, stream);

  prep_w<<<576, 256, 0, stream>>>(Wz_w, Wr_w, Wh_w, wfrag);

  if (ws_size >= WS_M2) {
    xproj_gemm<<<BB * TT / 64, 256, 0, stream>>>(x, wfrag, Wz_b, Wr_b, Wh_b, xbase);
    gru1s<<<256, 256, 0, stream>>>(xbase, wfrag, hbuf, rhbuf, hfin, ctrl);
  } else if (ws_size >= WS_M1) {
    xprep<<<(BB * TT * FF / 8) / 256, 256, 0, stream>>>(x, xbase);
    gru_kernel<1><<<256, 256, 0, stream>>>(xbase, wfrag, hbuf, rhbuf, hfin, ctrl,
                                           Wz_b, Wr_b, Wh_b);
  } else {
    gru_kernel<0><<<256, 256, 0, stream>>>(x, wfrag, hbuf, rhbuf, hfin, ctrl,
                                           Wz_b, Wr_b, Wh_b);
  }
  fc_kernel<<<BB, 64, 0, stream>>>(hfin, fc_w, fc_b, (float*)d_out);
}